// Round 3
// baseline (354.202 us; speedup 1.0000x reference)
//
#include <hip/hip_runtime.h>
#include <hip/hip_bf16.h>
#include <math.h>

// Soft-argmax over corr (b=4, h1=64, w1=64, h2=64, w2=64) f32.
// One wave (64 lanes) per (b,h1,w1) row of 4096 f32 (16 KB).
// Lane l holds elements [ (k*64+l)*4 .. +3 ] for k=0..15 -> 16 float4 in regs.
// Single HBM pass: max reduce over regs, then exp + weighted sums over regs.
__global__ __launch_bounds__(256) void KernelSoftArgmax_kernel(
    const float* __restrict__ corr,
    const float* __restrict__ beta_log,
    const float* __restrict__ coords,
    float* __restrict__ out)
{
    __shared__ float sc[64];
    const int tid = threadIdx.x;
    if (tid < 64) sc[tid] = coords[tid];
    __syncthreads();

    const int lane = tid & 63;
    const int wave = tid >> 6;
    const int row  = (blockIdx.x << 2) + wave;   // 16384 rows total

    const float4* __restrict__ src =
        (const float4*)(corr + (size_t)row * 4096) + lane;

    // 16 independent coalesced 16B loads (wave reads 1KB contiguous per k)
    float4 v[16];
#pragma unroll
    for (int k = 0; k < 16; ++k) v[k] = src[k * 64];

    const float scale = __expf(-beta_log[0]);   // 1/beta, always > 0

    // ---- max over the row ----
    float m = -INFINITY;
#pragma unroll
    for (int k = 0; k < 16; ++k)
        m = fmaxf(m, fmaxf(fmaxf(v[k].x, v[k].y), fmaxf(v[k].z, v[k].w)));
#pragma unroll
    for (int off = 32; off >= 1; off >>= 1)
        m = fmaxf(m, __shfl_xor(m, off, 64));
    m *= scale;  // scale>0 so max commutes with scaling

    // coordinate weights: element e=(k*64+lane)*4+j -> W=e&63, H=e>>6
    //   W = (lane*4+j)&63   (k-independent)
    //   H = k*4 + (lane>>4)
    const float cx0 = sc[(lane * 4 + 0) & 63];
    const float cx1 = sc[(lane * 4 + 1) & 63];
    const float cx2 = sc[(lane * 4 + 2) & 63];
    const float cx3 = sc[(lane * 4 + 3) & 63];
    const int hoff = lane >> 4;

    float s = 0.f, sx = 0.f, sy = 0.f;
#pragma unroll
    for (int k = 0; k < 16; ++k) {
        const float cy = sc[k * 4 + hoff];
        const float e0 = __expf(fmaf(v[k].x, scale, -m));
        const float e1 = __expf(fmaf(v[k].y, scale, -m));
        const float e2 = __expf(fmaf(v[k].z, scale, -m));
        const float e3 = __expf(fmaf(v[k].w, scale, -m));
        const float es = (e0 + e1) + (e2 + e3);
        s += es;
        sx = fmaf(e0, cx0, sx);
        sx = fmaf(e1, cx1, sx);
        sx = fmaf(e2, cx2, sx);
        sx = fmaf(e3, cx3, sx);
        sy = fmaf(es, cy, sy);
    }

    // ---- wave reductions ----
#pragma unroll
    for (int off = 32; off >= 1; off >>= 1) {
        s  += __shfl_xor(s,  off, 64);
        sx += __shfl_xor(sx, off, 64);
        sy += __shfl_xor(sy, off, 64);
    }

    if (lane == 0) {
        const float inv = 1.0f / s;
        out[row * 2 + 0] = sx * inv;   // grid_x (weighted by coords[W])
        out[row * 2 + 1] = sy * inv;   // grid_y (weighted by coords[H])
    }
}

extern "C" void kernel_launch(void* const* d_in, const int* in_sizes, int n_in,
                              void* d_out, int out_size, void* d_ws, size_t ws_size,
                              hipStream_t stream) {
    const float* corr     = (const float*)d_in[0];
    const float* beta_log = (const float*)d_in[1];
    const float* coords   = (const float*)d_in[2];
    float* out            = (float*)d_out;

    // 16384 rows, 1 wave/row, 4 waves/block -> 4096 blocks
    KernelSoftArgmax_kernel<<<4096, 256, 0, stream>>>(corr, beta_log, coords, out);
}